// Round 3
// baseline (495.618 us; speedup 1.0000x reference)
//
#include <hip/hip_runtime.h>
#include <hip/hip_bf16.h>

typedef __hip_bfloat16 bf16;
typedef __attribute__((ext_vector_type(8))) short bf16x8;  // 8 bf16 = 16B
typedef __attribute__((ext_vector_type(4))) float f32x4;

__device__ __forceinline__ float fsigmoid(float x) { return 1.0f / (1.0f + __expf(-x)); }
__device__ __forceinline__ float ftanh(float x)    { return 1.0f - 2.0f / (__expf(2.0f * x) + 1.0f); }

// pack 8 fp32 -> 8 bf16 (truncation; compiler folds each pair to v_perm)
__device__ __forceinline__ bf16x8 pack8(float4 lo, float4 hi) {
  union { bf16x8 v; unsigned int u[4]; } r;
  r.u[0] = (__float_as_uint(lo.y) & 0xFFFF0000u) | (__float_as_uint(lo.x) >> 16);
  r.u[1] = (__float_as_uint(lo.w) & 0xFFFF0000u) | (__float_as_uint(lo.z) >> 16);
  r.u[2] = (__float_as_uint(hi.y) & 0xFFFF0000u) | (__float_as_uint(hi.x) >> 16);
  r.u[3] = (__float_as_uint(hi.w) & 0xFFFF0000u) | (__float_as_uint(hi.z) >> 16);
  return r.v;
}

__device__ __forceinline__ float loadf(const void* p, size_t i, bool isf32) {
  return isf32 ? ((const float*)p)[i] : __bfloat162float(((const bf16*)p)[i]);
}

// Tile: 128 batch-rows x 128 cols (= 4 gates x 32 h), K = 2048 = [x | h], BK = 64.
// 256 threads = 4 waves; wave quadrant: rows 64*(w>>1), cols 64*(w&1).
// B-tile row n: gate = n>>5 (f,i,g,o). Wave w stages gate w's weights.
// LDS A/B: [row][64] bf16, 16B-chunk XOR-swizzled: LDS[row][c] = global chunk c^(row&7).
// Input dtype (fp32 vs bf16) detected at runtime from bit patterns of x.
__global__ __launch_bounds__(256) void lstm_fused(
    const void* __restrict__ xv, const void* __restrict__ hv, const void* __restrict__ cv,
    const void* __restrict__ wfi, const void* __restrict__ bfi, const void* __restrict__ wfh, const void* __restrict__ bfh,
    const void* __restrict__ wii, const void* __restrict__ bii, const void* __restrict__ wih, const void* __restrict__ bih,
    const void* __restrict__ wgi, const void* __restrict__ bgi, const void* __restrict__ wgh, const void* __restrict__ bgh,
    const void* __restrict__ woi, const void* __restrict__ boi, const void* __restrict__ woh, const void* __restrict__ boh,
    void* __restrict__ outv)
{
  __shared__ __align__(16) char smem[33792];   // max(As+Bs = 32KB, Epi 64x132 f32)
  __shared__ int cnts[4];
  short* As = (short*)smem;                    // [128][64] bf16, chunk-swizzled
  short* Bs = As + 8192;
  float* Epi = (float*)smem;                   // [64][132] f32 (aliases staging)

  const int tid  = threadIdx.x;
  const int lane = tid & 63;
  const int w    = tid >> 6;
  const int l15  = lane & 15;
  const int quad = lane >> 4;
  const int rq   = w >> 1;
  const int cq   = w & 1;
  const int rowoff = lane >> 3;     // 0..7
  const int ch   = lane & 7;        // source 16B chunk within row
  const int dstch = ch ^ rowoff;

  // ---- dtype probe: even-indexed shorts of x[0:256] ----
  // bf16 data: exponent in [100,140] essentially always; fp32 low halves: ~16%.
  {
    const unsigned short* xs = (const unsigned short*)xv;
    int e = (xs[2 * tid] >> 7) & 0xFF;
    unsigned long long m = __ballot(e >= 100 && e <= 140);
    if (lane == 0) cnts[w] = __popcll(m);
  }
  __syncthreads();
  const bool isf32 = (cnts[0] + cnts[1] + cnts[2] + cnts[3]) < 192;

  const int bg0 = blockIdx.y << 7;  // batch-row base
  const int hb  = blockIdx.x << 5;  // h base

  const void* WgI = (w == 0) ? wfi : (w == 1) ? wii : (w == 2) ? wgi : woi;
  const void* WgH = (w == 0) ? wfh : (w == 1) ? wih : (w == 2) ? wgh : woh;

  f32x4 acc[4][4];
#pragma unroll
  for (int i = 0; i < 4; ++i)
#pragma unroll
    for (int j = 0; j < 4; ++j) acc[i][j] = (f32x4){0.f, 0.f, 0.f, 0.f};

  const int arow = (rq * 64 + l15) * 64;
  const int brow = (cq * 64 + l15) * 64;
  const int sw   = l15 & 7;
  const int c0   = ((0 + quad) ^ sw) << 3;
  const int c1   = ((4 + quad) ^ sw) << 3;

  for (int kt = 0; kt < 32; ++kt) {
    const int kc = (kt & 15) << 6;
    const void* Ap = (kt < 16) ? xv : hv;
    const void* Bp = (kt < 16) ? WgI : WgH;
    const size_t abase = (size_t)bg0 * 1024 + kc;
    const size_t bbase = (size_t)hb * 1024 + kc;

    bf16x8 ra[4], rb[4];
    if (isf32) {
#pragma unroll
      for (int q = 0; q < 4; ++q) {
        const int u = (w << 2) + q;
        const float* pa = (const float*)Ap + abase + (size_t)((u << 3) + rowoff) * 1024 + (ch << 3);
        const float* pb = (const float*)Bp + bbase + (size_t)((q << 3) + rowoff) * 1024 + (ch << 3);
        float4 a0 = *(const float4*)pa, a1 = *(const float4*)(pa + 4);
        float4 b0 = *(const float4*)pb, b1 = *(const float4*)(pb + 4);
        ra[q] = pack8(a0, a1);
        rb[q] = pack8(b0, b1);
      }
    } else {
#pragma unroll
      for (int q = 0; q < 4; ++q) {
        const int u = (w << 2) + q;
        ra[q] = *(const bf16x8*)((const bf16*)Ap + abase + (size_t)((u << 3) + rowoff) * 1024 + (ch << 3));
        rb[q] = *(const bf16x8*)((const bf16*)Bp + bbase + (size_t)((q << 3) + rowoff) * 1024 + (ch << 3));
      }
    }
    __syncthreads();   // previous tile's LDS reads done before overwrite
#pragma unroll
    for (int q = 0; q < 4; ++q) {
      const int u = (w << 2) + q;
      *(bf16x8*)(As + (u * 8 + rowoff) * 64 + (dstch << 3)) = ra[q];
      *(bf16x8*)(Bs + (u * 8 + rowoff) * 64 + (dstch << 3)) = rb[q];
    }
    __syncthreads();   // staged data visible

#pragma unroll
    for (int s = 0; s < 2; ++s) {
      const int cs = s ? c1 : c0;
      bf16x8 a[4], b[4];
#pragma unroll
      for (int i = 0; i < 4; ++i) a[i] = *(const bf16x8*)(As + arow + i * 1024 + cs);
#pragma unroll
      for (int j = 0; j < 4; ++j) b[j] = *(const bf16x8*)(Bs + brow + j * 1024 + cs);
#pragma unroll
      for (int i = 0; i < 4; ++i)
#pragma unroll
        for (int j = 0; j < 4; ++j)
          acc[i][j] = __builtin_amdgcn_mfma_f32_16x16x32_bf16(a[i], b[j], acc[i][j], 0, 0, 0);
    }
  }

  // ---- epilogue ----
  // col n = cq*64 + 16j + l15 -> gate = cq*2 + (j>>1), h = hb + (j&1)*16 + l15
  const void* bAi = cq ? bgi : bfi;
  const void* bAh = cq ? bgh : bfh;
  const void* bBi = cq ? boi : bii;
  const void* bBh = cq ? boh : bih;
  float biasv[4];
  biasv[0] = loadf(bAi, hb + l15, isf32)      + loadf(bAh, hb + l15, isf32);
  biasv[1] = loadf(bAi, hb + 16 + l15, isf32) + loadf(bAh, hb + 16 + l15, isf32);
  biasv[2] = loadf(bBi, hb + l15, isf32)      + loadf(bBh, hb + l15, isf32);
  biasv[3] = loadf(bBi, hb + 16 + l15, isf32) + loadf(bBh, hb + 16 + l15, isf32);

  const size_t outCT = (size_t)8192 * 1024;

#pragma unroll
  for (int p = 0; p < 2; ++p) {
    __syncthreads();   // p=0: GEMM LDS reads done; p=1: previous combine reads done
    if (rq == p) {
#pragma unroll
      for (int j = 0; j < 4; ++j) {
        const int  n  = cq * 64 + j * 16 + l15;
        const bool ut = (cq == 1) && (j < 2);          // gate g -> tanh
        const float bj = biasv[j];
#pragma unroll
        for (int i = 0; i < 4; ++i)
#pragma unroll
          for (int r = 0; r < 4; ++r) {
            const float v = acc[i][j][r] + bj;
            Epi[(i * 16 + quad * 4 + r) * 132 + n] = ut ? ftanh(v) : fsigmoid(v);
          }
      }
    }
    __syncthreads();
#pragma unroll
    for (int it = 0; it < 8; ++it) {
      const int pair = it * 256 + tid;
      const int row  = pair >> 5;
      const int hl   = pair & 31;
      const float fv = Epi[row * 132 + hl];
      const float iv = Epi[row * 132 + 32 + hl];
      const float gv = Epi[row * 132 + 64 + hl];
      const float ov = Epi[row * 132 + 96 + hl];
      const size_t idx = (size_t)(bg0 + p * 64 + row) * 1024 + hb + hl;
      const float cvv = loadf(cv, idx, isf32);
      const float ctv = fv * cvv + iv * gv;
      const float htv = ov * ftanh(ctv);
      if (isf32) {
        ((float*)outv)[idx]         = htv;
        ((float*)outv)[outCT + idx] = ctv;
      } else {
        ((bf16*)outv)[idx]         = __float2bfloat16(htv);
        ((bf16*)outv)[outCT + idx] = __float2bfloat16(ctv);
      }
    }
  }
}

extern "C" void kernel_launch(void* const* d_in, const int* in_sizes, int n_in,
                              void* d_out, int out_size, void* d_ws, size_t ws_size,
                              hipStream_t stream) {
  dim3 grid(32, 64);   // 32 h-tiles x 64 batch-tiles = 2048 blocks
  dim3 block(256);
  lstm_fused<<<grid, block, 0, stream>>>(
      d_in[0], d_in[1], d_in[2],
      d_in[3], d_in[4], d_in[5], d_in[6],
      d_in[7], d_in[8], d_in[9], d_in[10],
      d_in[11], d_in[12], d_in[13], d_in[14],
      d_in[15], d_in[16], d_in[17], d_in[18],
      d_out);
}

// Round 4
// 478.284 us; speedup vs baseline: 1.0362x; 1.0362x over previous
//
#include <hip/hip_runtime.h>
#include <hip/hip_bf16.h>

typedef __hip_bfloat16 bf16;
typedef __attribute__((ext_vector_type(8))) short bf16x8;  // 8 bf16 = 16B
typedef __attribute__((ext_vector_type(4))) float f32x4;

__device__ __forceinline__ float fsigmoid(float x) { return 1.0f / (1.0f + __expf(-x)); }
__device__ __forceinline__ float ftanh(float x)    { return 1.0f - 2.0f / (__expf(2.0f * x) + 1.0f); }

// pack 8 fp32 -> 8 bf16 (truncation; folds to v_perm pairs)
__device__ __forceinline__ bf16x8 pack8(float4 lo, float4 hi) {
  union { bf16x8 v; unsigned int u[4]; } r;
  r.u[0] = (__float_as_uint(lo.y) & 0xFFFF0000u) | (__float_as_uint(lo.x) >> 16);
  r.u[1] = (__float_as_uint(lo.w) & 0xFFFF0000u) | (__float_as_uint(lo.z) >> 16);
  r.u[2] = (__float_as_uint(hi.y) & 0xFFFF0000u) | (__float_as_uint(hi.x) >> 16);
  r.u[3] = (__float_as_uint(hi.w) & 0xFFFF0000u) | (__float_as_uint(hi.z) >> 16);
  return r.v;
}

// Tile: 128 batch-rows x 128 cols (= 4 gates x 32 h), K = 2048 = [x | h], BK = 64.
// 256 threads = 4 waves; wave quadrant: rows 64*(w>>1), cols 64*(w&1).
// B-tile row n: gate = n>>5 (f,i,g,o). Wave w stages gate w's weights.
// LDS A/B: [row][64] bf16, 16B-chunk XOR-swizzled: LDS[row][c] = global chunk c^(row&7).
// fp32 inputs/outputs (confirmed R3: WRITE_SIZE=64MiB); bf16 internal via truncation.
// K-loop is software-pipelined: kt+1's global loads issue before kt's MFMA bundle,
// hiding global latency behind compute (single register buffer: ds_write consumes
// the regs before the reissue, so no double-buffer needed).
__global__ __launch_bounds__(256) void lstm_fused(
    const float* __restrict__ x, const float* __restrict__ h, const float* __restrict__ c,
    const float* __restrict__ wfi, const float* __restrict__ bfi, const float* __restrict__ wfh, const float* __restrict__ bfh,
    const float* __restrict__ wii, const float* __restrict__ bii, const float* __restrict__ wih, const float* __restrict__ bih,
    const float* __restrict__ wgi, const float* __restrict__ bgi, const float* __restrict__ wgh, const float* __restrict__ bgh,
    const float* __restrict__ woi, const float* __restrict__ boi, const float* __restrict__ woh, const float* __restrict__ boh,
    float* __restrict__ out)
{
  __shared__ __align__(16) char smem[33792];   // max(As+Bs = 32KB, Epi 64x132 f32)
  short* As = (short*)smem;                    // [128][64] bf16, chunk-swizzled
  short* Bs = As + 8192;
  float* Epi = (float*)smem;                   // [64][132] f32 (aliases staging)

  const int tid  = threadIdx.x;
  const int lane = tid & 63;
  const int w    = tid >> 6;
  const int l15  = lane & 15;
  const int quad = lane >> 4;
  const int rq   = w >> 1;
  const int cq   = w & 1;
  const int rowoff = lane >> 3;     // 0..7
  const int ch   = lane & 7;        // source 16B chunk within row
  const int dstch = ch ^ rowoff;

  const int bg0 = blockIdx.y << 7;  // batch-row base
  const int hb  = blockIdx.x << 5;  // h base

  const float* WgI = (w == 0) ? wfi : (w == 1) ? wii : (w == 2) ? wgi : woi;
  const float* WgH = (w == 0) ? wfh : (w == 1) ? wih : (w == 2) ? wgh : woh;

  // per-thread constant element offsets into a 128x(1024-row-stride) fp32 tile
  size_t aoff[4], boff[4];
#pragma unroll
  for (int q = 0; q < 4; ++q) {
    const int u = (w << 2) + q;
    aoff[q] = (size_t)((u << 3) + rowoff) * 1024 + (ch << 3);
    boff[q] = (size_t)((q << 3) + rowoff) * 1024 + (ch << 3);
  }

  f32x4 acc[4][4];
#pragma unroll
  for (int i = 0; i < 4; ++i)
#pragma unroll
    for (int j = 0; j < 4; ++j) acc[i][j] = (f32x4){0.f, 0.f, 0.f, 0.f};

  const int arow = (rq * 64 + l15) * 64;
  const int brow = (cq * 64 + l15) * 64;
  const int sw   = l15 & 7;
  const int c0   = ((0 + quad) ^ sw) << 3;
  const int c1   = ((4 + quad) ^ sw) << 3;

  float4 A0[4], A1[4], B0[4], B1[4];   // prefetch buffer (64 VGPRs)
  auto issue = [&](int KT) {
    const float* Ab = ((KT < 16) ? x : h)     + (size_t)bg0 * 1024 + ((KT & 15) << 6);
    const float* Bb = ((KT < 16) ? WgI : WgH) + (size_t)hb  * 1024 + ((KT & 15) << 6);
#pragma unroll
    for (int q = 0; q < 4; ++q) {
      const float* pa = Ab + aoff[q];
      const float* pb = Bb + boff[q];
      A0[q] = *(const float4*)pa; A1[q] = *(const float4*)(pa + 4);
      B0[q] = *(const float4*)pb; B1[q] = *(const float4*)(pb + 4);
    }
  };

  issue(0);
  for (int kt = 0; kt < 32; ++kt) {
    __syncthreads();   // previous tile's LDS reads done before overwrite
#pragma unroll
    for (int q = 0; q < 4; ++q) {
      const int u = (w << 2) + q;
      *(bf16x8*)(As + (u * 8 + rowoff) * 64 + (dstch << 3)) = pack8(A0[q], A1[q]);
      *(bf16x8*)(Bs + (u * 8 + rowoff) * 64 + (dstch << 3)) = pack8(B0[q], B1[q]);
    }
    __syncthreads();   // staged data visible
    if (kt < 31) issue(kt + 1);   // prefetch: latency overlaps the MFMA bundle below

#pragma unroll
    for (int s = 0; s < 2; ++s) {
      const int cs = s ? c1 : c0;
      bf16x8 a[4], b[4];
#pragma unroll
      for (int i = 0; i < 4; ++i) a[i] = *(const bf16x8*)(As + arow + i * 1024 + cs);
#pragma unroll
      for (int j = 0; j < 4; ++j) b[j] = *(const bf16x8*)(Bs + brow + j * 1024 + cs);
#pragma unroll
      for (int i = 0; i < 4; ++i)
#pragma unroll
        for (int j = 0; j < 4; ++j)
          acc[i][j] = __builtin_amdgcn_mfma_f32_16x16x32_bf16(a[i], b[j], acc[i][j], 0, 0, 0);
    }
  }

  // ---- epilogue ----
  // col n = cq*64 + 16j + l15 -> gate = cq*2 + (j>>1), h = hb + (j&1)*16 + l15
  const float* bAi = cq ? bgi : bfi;
  const float* bAh = cq ? bgh : bfh;
  const float* bBi = cq ? boi : bii;
  const float* bBh = cq ? boh : bih;
  float biasv[4];
  biasv[0] = bAi[hb + l15]      + bAh[hb + l15];
  biasv[1] = bAi[hb + 16 + l15] + bAh[hb + 16 + l15];
  biasv[2] = bBi[hb + l15]      + bBh[hb + l15];
  biasv[3] = bBi[hb + 16 + l15] + bBh[hb + 16 + l15];

  const size_t outCT = (size_t)8192 * 1024;

#pragma unroll
  for (int p = 0; p < 2; ++p) {
    __syncthreads();   // p=0: GEMM LDS reads done; p=1: previous combine reads done
    if (rq == p) {
#pragma unroll
      for (int j = 0; j < 4; ++j) {
        const int  n  = cq * 64 + j * 16 + l15;
        const bool ut = (cq == 1) && (j < 2);          // gate g -> tanh
        const float bj = biasv[j];
#pragma unroll
        for (int i = 0; i < 4; ++i)
#pragma unroll
          for (int r = 0; r < 4; ++r) {
            const float v = acc[i][j][r] + bj;
            Epi[(i * 16 + quad * 4 + r) * 132 + n] = ut ? ftanh(v) : fsigmoid(v);
          }
      }
    }
    __syncthreads();
#pragma unroll
    for (int it = 0; it < 8; ++it) {
      const int pair = it * 256 + tid;
      const int row  = pair >> 5;
      const int hl   = pair & 31;
      const float fv = Epi[row * 132 + hl];
      const float iv = Epi[row * 132 + 32 + hl];
      const float gv = Epi[row * 132 + 64 + hl];
      const float ov = Epi[row * 132 + 96 + hl];
      const size_t idx = (size_t)(bg0 + p * 64 + row) * 1024 + hb + hl;
      const float cvv = c[idx];
      const float ctv = fv * cvv + iv * gv;
      const float htv = ov * ftanh(ctv);
      out[idx]         = htv;   // ht (output 0)
      out[outCT + idx] = ctv;   // ct (output 1)
    }
  }
}

extern "C" void kernel_launch(void* const* d_in, const int* in_sizes, int n_in,
                              void* d_out, int out_size, void* d_ws, size_t ws_size,
                              hipStream_t stream) {
  const float* p[19];
  for (int i = 0; i < 19; ++i) p[i] = (const float*)d_in[i];
  dim3 grid(32, 64);   // 32 h-tiles x 64 batch-tiles = 2048 blocks
  dim3 block(256);
  lstm_fused<<<grid, block, 0, stream>>>(
      p[0], p[1], p[2],
      p[3], p[4], p[5], p[6],
      p[7], p[8], p[9], p[10],
      p[11], p[12], p[13], p[14],
      p[15], p[16], p[17], p[18],
      (float*)d_out);
}

// Round 5
// 341.330 us; speedup vs baseline: 1.4520x; 1.4012x over previous
//
#include <hip/hip_runtime.h>
#include <hip/hip_bf16.h>

typedef __hip_bfloat16 bf16;
typedef __attribute__((ext_vector_type(8))) short bf16x8;  // 8 bf16 = 16B
typedef __attribute__((ext_vector_type(4))) float f32x4;

#define AS1 __attribute__((address_space(1)))
#define AS3 __attribute__((address_space(3)))

__device__ __forceinline__ void async16(const void* g, void* l) {
  __builtin_amdgcn_global_load_lds((const AS1 void*)g, (AS3 void*)l, 16, 0, 0);
}

__device__ __forceinline__ float fsigmoid(float x) { return 1.0f / (1.0f + __expf(-x)); }
__device__ __forceinline__ float ftanh(float x)    { return 1.0f - 2.0f / (__expf(2.0f * x) + 1.0f); }

__device__ __forceinline__ bf16x8 pack8(float4 lo, float4 hi) {
  union { bf16x8 v; unsigned int u[4]; } r;
  r.u[0] = (__float_as_uint(lo.y) & 0xFFFF0000u) | (__float_as_uint(lo.x) >> 16);
  r.u[1] = (__float_as_uint(lo.w) & 0xFFFF0000u) | (__float_as_uint(lo.z) >> 16);
  r.u[2] = (__float_as_uint(hi.y) & 0xFFFF0000u) | (__float_as_uint(hi.x) >> 16);
  r.u[3] = (__float_as_uint(hi.w) & 0xFFFF0000u) | (__float_as_uint(hi.z) >> 16);
  return r.v;
}

// ---- prep: fp32 -> bf16 into ws: [x 8M][h 8M][wfi wii wgi woi wfh wih wgh woh, 1M each]
__global__ __launch_bounds__(256) void prep_bf16(
    const float* __restrict__ x, const float* __restrict__ h,
    const float* __restrict__ w0, const float* __restrict__ w1,
    const float* __restrict__ w2, const float* __restrict__ w3,
    const float* __restrict__ w4, const float* __restrict__ w5,
    const float* __restrict__ w6, const float* __restrict__ w7,
    bf16* __restrict__ dst)
{
  const int NC = 3 * 1024 * 1024;   // 24M elems / 8
  for (int ci = blockIdx.x * 256 + threadIdx.x; ci < NC; ci += gridDim.x * 256) {
    size_t e = (size_t)ci << 3;
    const float* src; size_t off;
    if (e < (size_t)(8u << 20))       { src = x; off = e; }
    else if (e < (size_t)(16u << 20)) { src = h; off = e - (8u << 20); }
    else {
      size_t we = e - (16u << 20);
      int g = (int)(we >> 20); off = we & ((1u << 20) - 1);
      src = g==0?w0: g==1?w1: g==2?w2: g==3?w3: g==4?w4: g==5?w5: g==6?w6: w7;
    }
    float4 lo = *(const float4*)(src + off);
    float4 hi = *(const float4*)(src + off + 4);
    *(bf16x8*)(dst + e) = pack8(lo, hi);
  }
}

// ---- main: 128x128 tile, BK=64, DMA staging from bf16 ws, fused gate epilogue ----
// LDS[row][c] = global chunk c^(row&7); DMA dest = base + lane*16 => row u*8+(lane>>3),
// chunk lane&7 => source chunk (lane&7)^(lane>>3). Frag reads at chunk g^(row&7).
__global__ __launch_bounds__(256, 3) void lstm_mfma(
    const bf16* __restrict__ ws,
    const float* __restrict__ c,
    const float* __restrict__ bfi, const float* __restrict__ bfh,
    const float* __restrict__ bii, const float* __restrict__ bih,
    const float* __restrict__ bgi, const float* __restrict__ bgh,
    const float* __restrict__ boi, const float* __restrict__ boh,
    float* __restrict__ out)
{
  __shared__ __align__(16) char smem[33792];   // As+Bs 32KB; Epi 64x132 f32 aliases
  short* As = (short*)smem;                    // [128][64] bf16, chunk-swizzled
  short* Bs = As + 8192;
  float* Epi = (float*)smem;

  const int tid  = threadIdx.x;
  const int lane = tid & 63;
  const int w    = tid >> 6;
  const int l15  = lane & 15;
  const int quad = lane >> 4;
  const int rq   = w >> 1;
  const int cq   = w & 1;
  const int rowoff = lane >> 3;                     // dest row within 8-row group
  const int csw  = (((lane & 7) ^ rowoff) << 3);    // swizzled SOURCE chunk offset (elems)

  const int bg0 = blockIdx.y << 7;
  const int hb  = blockIdx.x << 5;

  const bf16* xb   = ws;                              // 8M
  const bf16* hbuf = ws + (size_t)(8u << 20);         // 8M
  const bf16* wb   = ws + (size_t)(16u << 20);        // 8 x 1M
  const bf16* WgIb = wb + (size_t)w * (1u << 20);     // gate w input-weights
  const bf16* WgHb = wb + (size_t)(4 + w) * (1u << 20);

  f32x4 acc[4][4];
#pragma unroll
  for (int i = 0; i < 4; ++i)
#pragma unroll
    for (int j = 0; j < 4; ++j) acc[i][j] = (f32x4){0.f, 0.f, 0.f, 0.f};

  const int arow = (rq * 64 + l15) * 64;
  const int brow = (cq * 64 + l15) * 64;
  const int sw   = l15 & 7;
  const int c0   = ((0 + quad) ^ sw) << 3;
  const int c1   = ((4 + quad) ^ sw) << 3;

  for (int kt = 0; kt < 32; ++kt) {
    const int kc = (kt & 15) << 6;
    const bf16* Ap = (kt < 16 ? xb : hbuf) + (size_t)bg0 * 1024 + kc;
    const bf16* Bp = (kt < 16 ? WgIb : WgHb) + (size_t)hb * 1024 + kc;

    __syncthreads();   // previous tile's LDS reads done before overwrite
#pragma unroll
    for (int q = 0; q < 4; ++q) {
      const int u = (w << 2) + q;
      async16(Ap + (size_t)((u << 3) + rowoff) * 1024 + csw, (char*)smem + u * 1024);
      async16(Bp + (size_t)((q << 3) + rowoff) * 1024 + csw, (char*)smem + 16384 + u * 1024);
    }
    __syncthreads();   // vmcnt drained -> staged data visible

#pragma unroll
    for (int s = 0; s < 2; ++s) {
      const int cs = s ? c1 : c0;
      bf16x8 a[4], b[4];
#pragma unroll
      for (int i = 0; i < 4; ++i) a[i] = *(const bf16x8*)(As + arow + i * 1024 + cs);
#pragma unroll
      for (int j = 0; j < 4; ++j) b[j] = *(const bf16x8*)(Bs + brow + j * 1024 + cs);
#pragma unroll
      for (int i = 0; i < 4; ++i)
#pragma unroll
        for (int j = 0; j < 4; ++j)
          acc[i][j] = __builtin_amdgcn_mfma_f32_16x16x32_bf16(a[i], b[j], acc[i][j], 0, 0, 0);
    }
  }

  // col n = cq*64 + 16j + l15 -> gate = cq*2 + (j>>1), h = hb + (j&1)*16 + l15
  const float* bAi = cq ? bgi : bfi;
  const float* bAh = cq ? bgh : bfh;
  const float* bBi = cq ? boi : bii;
  const float* bBh = cq ? boh : bih;
  float biasv[4];
  biasv[0] = bAi[hb + l15]      + bAh[hb + l15];
  biasv[1] = bAi[hb + 16 + l15] + bAh[hb + 16 + l15];
  biasv[2] = bBi[hb + l15]      + bBh[hb + l15];
  biasv[3] = bBi[hb + 16 + l15] + bBh[hb + 16 + l15];

  const size_t outCT = (size_t)8192 * 1024;

#pragma unroll
  for (int p = 0; p < 2; ++p) {
    __syncthreads();
    if (rq == p) {
#pragma unroll
      for (int j = 0; j < 4; ++j) {
        const int  n  = cq * 64 + j * 16 + l15;
        const bool ut = (cq == 1) && (j < 2);          // gate g -> tanh
        const float bj = biasv[j];
#pragma unroll
        for (int i = 0; i < 4; ++i)
#pragma unroll
          for (int r = 0; r < 4; ++r) {
            const float v = acc[i][j][r] + bj;
            Epi[(i * 16 + quad * 4 + r) * 132 + n] = ut ? ftanh(v) : fsigmoid(v);
          }
      }
    }
    __syncthreads();
#pragma unroll
    for (int it = 0; it < 8; ++it) {
      const int pair = it * 256 + tid;
      const int row  = pair >> 5;
      const int hl   = pair & 31;
      const float fv = Epi[row * 132 + hl];
      const float iv = Epi[row * 132 + 32 + hl];
      const float gv = Epi[row * 132 + 64 + hl];
      const float ov = Epi[row * 132 + 96 + hl];
      const size_t idx = (size_t)(bg0 + p * 64 + row) * 1024 + hb + hl;
      const float ctv = fv * c[idx] + iv * gv;
      const float htv = ov * ftanh(ctv);
      out[idx]         = htv;
      out[outCT + idx] = ctv;
    }
  }
}

// ---- fallback (round-4 kernel, register staging) if ws too small ----
__global__ __launch_bounds__(256) void lstm_fused(
    const float* __restrict__ x, const float* __restrict__ h, const float* __restrict__ c,
    const float* __restrict__ wfi, const float* __restrict__ bfi, const float* __restrict__ wfh, const float* __restrict__ bfh,
    const float* __restrict__ wii, const float* __restrict__ bii, const float* __restrict__ wih, const float* __restrict__ bih,
    const float* __restrict__ wgi, const float* __restrict__ bgi, const float* __restrict__ wgh, const float* __restrict__ bgh,
    const float* __restrict__ woi, const float* __restrict__ boi, const float* __restrict__ woh, const float* __restrict__ boh,
    float* __restrict__ out)
{
  __shared__ __align__(16) char smem[33792];
  short* As = (short*)smem;
  short* Bs = As + 8192;
  float* Epi = (float*)smem;

  const int tid  = threadIdx.x;
  const int lane = tid & 63;
  const int w    = tid >> 6;
  const int l15  = lane & 15;
  const int quad = lane >> 4;
  const int rq   = w >> 1;
  const int cq   = w & 1;
  const int rowoff = lane >> 3;
  const int ch   = lane & 7;
  const int dstch = ch ^ rowoff;

  const int bg0 = blockIdx.y << 7;
  const int hb  = blockIdx.x << 5;

  const float* WgI = (w == 0) ? wfi : (w == 1) ? wii : (w == 2) ? wgi : woi;
  const float* WgH = (w == 0) ? wfh : (w == 1) ? wih : (w == 2) ? wgh : woh;

  size_t aoff[4], boff[4];
#pragma unroll
  for (int q = 0; q < 4; ++q) {
    const int u = (w << 2) + q;
    aoff[q] = (size_t)((u << 3) + rowoff) * 1024 + (ch << 3);
    boff[q] = (size_t)((q << 3) + rowoff) * 1024 + (ch << 3);
  }

  f32x4 acc[4][4];
#pragma unroll
  for (int i = 0; i < 4; ++i)
#pragma unroll
    for (int j = 0; j < 4; ++j) acc[i][j] = (f32x4){0.f, 0.f, 0.f, 0.f};

  const int arow = (rq * 64 + l15) * 64;
  const int brow = (cq * 64 + l15) * 64;
  const int sw   = l15 & 7;
  const int c0   = ((0 + quad) ^ sw) << 3;
  const int c1   = ((4 + quad) ^ sw) << 3;

  float4 A0[4], A1[4], B0[4], B1[4];
  auto issue = [&](int KT) {
    const float* Ab = ((KT < 16) ? x : h)     + (size_t)bg0 * 1024 + ((KT & 15) << 6);
    const float* Bb = ((KT < 16) ? WgI : WgH) + (size_t)hb  * 1024 + ((KT & 15) << 6);
#pragma unroll
    for (int q = 0; q < 4; ++q) {
      const float* pa = Ab + aoff[q];
      const float* pb = Bb + boff[q];
      A0[q] = *(const float4*)pa; A1[q] = *(const float4*)(pa + 4);
      B0[q] = *(const float4*)pb; B1[q] = *(const float4*)(pb + 4);
    }
  };

  issue(0);
  for (int kt = 0; kt < 32; ++kt) {
    __syncthreads();
#pragma unroll
    for (int q = 0; q < 4; ++q) {
      const int u = (w << 2) + q;
      *(bf16x8*)(As + (u * 8 + rowoff) * 64 + (dstch << 3)) = pack8(A0[q], A1[q]);
      *(bf16x8*)(Bs + (u * 8 + rowoff) * 64 + (dstch << 3)) = pack8(B0[q], B1[q]);
    }
    __syncthreads();
    if (kt < 31) issue(kt + 1);

#pragma unroll
    for (int s = 0; s < 2; ++s) {
      const int cs = s ? c1 : c0;
      bf16x8 a[4], b[4];
#pragma unroll
      for (int i = 0; i < 4; ++i) a[i] = *(const bf16x8*)(As + arow + i * 1024 + cs);
#pragma unroll
      for (int j = 0; j < 4; ++j) b[j] = *(const bf16x8*)(Bs + brow + j * 1024 + cs);
#pragma unroll
      for (int i = 0; i < 4; ++i)
#pragma unroll
        for (int j = 0; j < 4; ++j)
          acc[i][j] = __builtin_amdgcn_mfma_f32_16x16x32_bf16(a[i], b[j], acc[i][j], 0, 0, 0);
    }
  }

  const float* bAi = cq ? bgi : bfi;
  const float* bAh = cq ? bgh : bfh;
  const float* bBi = cq ? boi : bii;
  const float* bBh = cq ? boh : bih;
  float biasv[4];
  biasv[0] = bAi[hb + l15]      + bAh[hb + l15];
  biasv[1] = bAi[hb + 16 + l15] + bAh[hb + 16 + l15];
  biasv[2] = bBi[hb + l15]      + bBh[hb + l15];
  biasv[3] = bBi[hb + 16 + l15] + bBh[hb + 16 + l15];

  const size_t outCT = (size_t)8192 * 1024;

#pragma unroll
  for (int p = 0; p < 2; ++p) {
    __syncthreads();
    if (rq == p) {
#pragma unroll
      for (int j = 0; j < 4; ++j) {
        const int  n  = cq * 64 + j * 16 + l15;
        const bool ut = (cq == 1) && (j < 2);
        const float bj = biasv[j];
#pragma unroll
        for (int i = 0; i < 4; ++i)
#pragma unroll
          for (int r = 0; r < 4; ++r) {
            const float v = acc[i][j][r] + bj;
            Epi[(i * 16 + quad * 4 + r) * 132 + n] = ut ? ftanh(v) : fsigmoid(v);
          }
      }
    }
    __syncthreads();
#pragma unroll
    for (int it = 0; it < 8; ++it) {
      const int pair = it * 256 + tid;
      const int row  = pair >> 5;
      const int hl   = pair & 31;
      const float fv = Epi[row * 132 + hl];
      const float iv = Epi[row * 132 + 32 + hl];
      const float gv = Epi[row * 132 + 64 + hl];
      const float ov = Epi[row * 132 + 96 + hl];
      const size_t idx = (size_t)(bg0 + p * 64 + row) * 1024 + hb + hl;
      const float ctv = fv * c[idx] + iv * gv;
      const float htv = ov * ftanh(ctv);
      out[idx]         = htv;
      out[outCT + idx] = ctv;
    }
  }
}

extern "C" void kernel_launch(void* const* d_in, const int* in_sizes, int n_in,
                              void* d_out, int out_size, void* d_ws, size_t ws_size,
                              hipStream_t stream) {
  const float* p[19];
  for (int i = 0; i < 19; ++i) p[i] = (const float*)d_in[i];
  dim3 grid(32, 64);
  dim3 block(256);
  const size_t need = (size_t)24 * 1024 * 1024 * sizeof(bf16);   // 48 MB
  if (ws_size >= need) {
    prep_bf16<<<dim3(2048), block, 0, stream>>>(
        p[0], p[1],
        p[3], p[7], p[11], p[15],     // wfi wii wgi woi
        p[5], p[9], p[13], p[17],     // wfh wih wgh woh
        (bf16*)d_ws);
    lstm_mfma<<<grid, block, 0, stream>>>(
        (const bf16*)d_ws, p[2],
        p[4], p[6], p[8], p[10], p[12], p[14], p[16], p[18],
        (float*)d_out);
  } else {
    lstm_fused<<<grid, block, 0, stream>>>(
        p[0], p[1], p[2],
        p[3], p[4], p[5], p[6],
        p[7], p[8], p[9], p[10],
        p[11], p[12], p[13], p[14],
        p[15], p[16], p[17], p[18],
        (float*)d_out);
  }
}